// Round 2
// baseline (65.281 us; speedup 1.0000x reference)
//
#include <hip/hip_runtime.h>
#include <math.h>

#define EPSF 1e-6f
#define CCF  0.01f
#define SQRT_C 0.1f

__device__ __forceinline__ float wred(float v) {
#pragma unroll
    for (int o = 32; o > 0; o >>= 1) v += __shfl_xor(v, o, 64);
    return v;
}

// rel_h = exp_map_zero(rel_embedding); store transposed (256 x 512) + y2[r]
__global__ void k_rel(const float* __restrict__ rel, float* __restrict__ rel_hT,
                      float* __restrict__ y2) {
    int r = blockIdx.x;   // 0..511
    int t = threadIdx.x;  // 0..63
    float v[4];
    float ss = 0.f;
#pragma unroll
    for (int i = 0; i < 4; ++i) {
        v[i] = rel[r * 256 + t + 64 * i];
        ss = fmaf(v[i], v[i], ss);
    }
    ss = wred(ss);
    float n = fmaxf(sqrtf(ss), EPSF);
    float s = tanhf(SQRT_C * n) / (SQRT_C * n);
#pragma unroll
    for (int i = 0; i < 4; ++i) {
        rel_hT[(size_t)(t + 64 * i) * 512 + r] = s * v[i];
    }
    if (t == 0) y2[r] = s * s * ss;
}

// gather entity rows + log_map_zero scaling. z<1024 -> s rows, z>=1024 -> o rows
__global__ void k_gather_log(const float* __restrict__ E,
                             const int* __restrict__ trip,
                             float* __restrict__ xs) {
    int z = blockIdx.x;        // 0..2047
    int b = z & 1023;
    int col = (z >> 10) ? 2 : 0;
    int idx = trip[b * 3 + col];
    idx = max(0, min(idx, 19999));   // defensive clamp, branch-free
    int t = threadIdx.x;
    const float* row = E + (size_t)idx * 256;
    float v[4];
    float ss = 0.f;
#pragma unroll
    for (int i = 0; i < 4; ++i) {
        v[i] = row[t + 64 * i];
        ss = fmaf(v[i], v[i], ss);
    }
    ss = wred(ss);
    float n = fmaxf(sqrtf(ss), EPSF);
    float arg = fminf(SQRT_C * n, 1.f - 1e-5f);
    float s = atanhf(arg) / (SQRT_C * n);
#pragma unroll
    for (int i = 0; i < 4; ++i) {
        xs[(size_t)z * 256 + t + 64 * i] = s * v[i];
    }
}

// xt = xs @ W  (rows 0..1023 use W_s, rows 1024..2047 use W_o). 8 rows/block.
__global__ __launch_bounds__(256) void k_gemm_w(const float* __restrict__ xs,
                                                const float* __restrict__ Ws,
                                                const float* __restrict__ Wo,
                                                float* __restrict__ xt) {
    __shared__ float A[8][256];
    int m0 = blockIdx.x * 8;
    const float* __restrict__ W = (m0 < 1024) ? Ws : Wo;
    int t = threadIdx.x;
#pragma unroll
    for (int m = 0; m < 8; ++m) A[m][t] = xs[(size_t)(m0 + m) * 256 + t];
    __syncthreads();
    float acc[8] = {};
#pragma unroll 4
    for (int k = 0; k < 256; ++k) {
        float w = W[(size_t)k * 256 + t];
#pragma unroll
        for (int m = 0; m < 8; ++m) acc[m] = fmaf(A[m][k], w, acc[m]);
    }
#pragma unroll
    for (int m = 0; m < 8; ++m) xt[(size_t)(m0 + m) * 256 + t] = acc[m];
}

// exp_map on s_tan/o_tan, mobius_add(-s_h, o_h) -> query + q2. One wave per row.
__global__ void k_query(const float* __restrict__ xt, float* __restrict__ query,
                        float* __restrict__ q2) {
    int b = blockIdx.x;   // 0..1023
    int t = threadIdx.x;  // 0..63
    float sv[4], ov[4];
    float sss = 0.f, sso = 0.f, sdot = 0.f;
#pragma unroll
    for (int i = 0; i < 4; ++i) {
        sv[i] = xt[(size_t)b * 256 + t + 64 * i];
        ov[i] = xt[(size_t)(1024 + b) * 256 + t + 64 * i];
        sss = fmaf(sv[i], sv[i], sss);
        sso = fmaf(ov[i], ov[i], sso);
        sdot = fmaf(sv[i], ov[i], sdot);
    }
    sss = wred(sss);
    sso = wred(sso);
    sdot = wred(sdot);
    float ns = fmaxf(sqrtf(sss), EPSF);
    float no = fmaxf(sqrtf(sso), EPSF);
    float scs = tanhf(SQRT_C * ns) / (SQRT_C * ns);
    float sco = tanhf(SQRT_C * no) / (SQRT_C * no);
    // x = -s_h, y = o_h
    float x2 = scs * scs * sss;
    float yy2 = sco * sco * sso;
    float xy = -scs * sco * sdot;
    float a1 = 1.f + 2.f * CCF * xy + CCF * yy2;
    float b1 = 1.f - CCF * x2;
    float den = 1.f + 2.f * CCF * xy + CCF * CCF * x2 * yy2 + EPSF;
    float rden = 1.f / den;
    float qq = 0.f;
#pragma unroll
    for (int i = 0; i < 4; ++i) {
        float num = a1 * (-scs * sv[i]) + b1 * (sco * ov[i]);
        float qv = num * rden;
        qq = fmaf(qv, qv, qq);
        query[(size_t)b * 256 + t + 64 * i] = qv;
    }
    qq = wred(qq);
    if (t == 0) q2[b] = qq;
}

// scores: G = query . rel_h^T, then closed-form mobius distance + bias.
__global__ __launch_bounds__(256) void k_scores(const float* __restrict__ query,
                                                const float* __restrict__ q2,
                                                const float* __restrict__ rel_hT,
                                                const float* __restrict__ y2,
                                                const float* __restrict__ rbias,
                                                float* __restrict__ out) {
    __shared__ float Q[8][256];
    __shared__ float q2s[8];
    int m0 = blockIdx.x * 8;  // 128 blocks
    int t = threadIdx.x;
#pragma unroll
    for (int m = 0; m < 8; ++m) Q[m][t] = query[(size_t)(m0 + m) * 256 + t];
    if (t < 8) q2s[t] = q2[m0 + t];
    __syncthreads();
#pragma unroll
    for (int jj = 0; jj < 2; ++jj) {
        int r = jj * 256 + t;
        float acc[8] = {};
#pragma unroll 4
        for (int k = 0; k < 256; ++k) {
            float w = rel_hT[(size_t)k * 512 + r];
#pragma unroll
            for (int m = 0; m < 8; ++m) acc[m] = fmaf(Q[m][k], w, acc[m]);
        }
        float y2r = y2[r];
        float rb = rbias[r];
#pragma unroll
        for (int m = 0; m < 8; ++m) {
            float xy = -acc[m];        // dot(-query, rel_h)
            float x2 = q2s[m];
            float a1 = 1.f + 2.f * CCF * xy + CCF * y2r;
            float b1 = 1.f - CCF * x2;
            float den = 1.f + 2.f * CCF * xy + CCF * CCF * x2 * y2r + EPSF;
            float num2 = a1 * a1 * x2 + 2.f * a1 * b1 * xy + b1 * b1 * y2r;
            out[(size_t)(m0 + m) * 512 + r] = -(num2 / (den * den)) + rb;
        }
    }
}

extern "C" void kernel_launch(void* const* d_in, const int* in_sizes, int n_in,
                              void* d_out, int out_size, void* d_ws, size_t ws_size,
                              hipStream_t stream) {
    const float* E = (const float*)d_in[0];          // 20000 x 256
    const float* rel = (const float*)d_in[1];        // 512 x 256
    const int* trip = (const int*)d_in[2];           // 1024 x 3 (int32 per harness)
    const float* Ws = (const float*)d_in[3];         // 256 x 256
    const float* Wo = (const float*)d_in[4];         // 256 x 256
    const float* rbias = (const float*)d_in[5];      // 512
    float* out = (float*)d_out;                      // 1024 x 512

    float* ws = (float*)d_ws;
    float* rel_hT = ws;                      // 256*512   = 131072
    float* y2     = rel_hT + 131072;         // 512
    float* xs     = y2 + 512;                // 2048*256  = 524288
    float* xt     = xs + 524288;             // 2048*256  = 524288
    float* query  = xt + 524288;             // 1024*256  = 262144
    float* q2     = query + 262144;          // 1024

    k_rel<<<512, 64, 0, stream>>>(rel, rel_hT, y2);
    k_gather_log<<<2048, 64, 0, stream>>>(E, trip, xs);
    k_gemm_w<<<256, 256, 0, stream>>>(xs, Ws, Wo, xt);
    k_query<<<1024, 64, 0, stream>>>(xt, query, q2);
    k_scores<<<128, 256, 0, stream>>>(query, q2, rel_hT, y2, rbias, out);
}

// Round 3
// 47.098 us; speedup vs baseline: 1.3861x; 1.3861x over previous
//
#include <hip/hip_runtime.h>
#include <math.h>

#define EPSF 1e-6f
#define CCF  0.01f
#define SQRT_C 0.1f

__device__ __forceinline__ float wred(float v) {
#pragma unroll
    for (int o = 32; o > 0; o >>= 1) v += __shfl_xor(v, o, 64);
    return v;
}

// rel_h = exp_map_zero(rel_embedding); store transposed (256 x 512) + y2[r].
// 128 blocks x 256 threads; wave w of block handles r = blk*4 + w.
__global__ __launch_bounds__(256) void k_rel(const float* __restrict__ rel,
                                             float* __restrict__ rel_hT,
                                             float* __restrict__ y2) {
    int wave = threadIdx.x >> 6, lane = threadIdx.x & 63;
    int r = blockIdx.x * 4 + wave;  // 0..511
    float v[4];
    float ss = 0.f;
#pragma unroll
    for (int i = 0; i < 4; ++i) {
        v[i] = rel[(size_t)r * 256 + lane + 64 * i];
        ss = fmaf(v[i], v[i], ss);
    }
    ss = wred(ss);
    float n = fmaxf(sqrtf(ss), EPSF);
    float s = tanhf(SQRT_C * n) / (SQRT_C * n);
#pragma unroll
    for (int i = 0; i < 4; ++i) {
        rel_hT[(size_t)(lane + 64 * i) * 512 + r] = s * v[i];
    }
    if (lane == 0) y2[r] = s * s * ss;
}

// Fully fused: gather -> log_map -> GEMV(W_s/W_o) -> exp_map+mobius(query)
// -> scores GEMV vs rel_hT -> closed-form distance + bias -> out.
// 256 blocks x 256 threads, 4 batch rows per block (1 block/CU).
__global__ __launch_bounds__(256) void k_main(const float* __restrict__ E,
                                              const int* __restrict__ trip,
                                              const float* __restrict__ Ws,
                                              const float* __restrict__ Wo,
                                              const float* __restrict__ rel_hT,
                                              const float* __restrict__ y2,
                                              const float* __restrict__ rbias,
                                              float* __restrict__ out) {
    __shared__ float A[8][256];     // rows 0-3: s rows, 4-7: o rows
    __shared__ float C[4][256];     // query rows
    __shared__ float scale[8];
    __shared__ float q2s[4];

    int b0 = blockIdx.x * 4;
    int t = threadIdx.x;
    int wave = t >> 6, lane = t & 63;

    // ---- gather raw entity rows ----
#pragma unroll
    for (int m = 0; m < 8; ++m) {
        int b = b0 + (m & 3);
        int col = (m >> 2) ? 2 : 0;
        int idx = trip[b * 3 + col];
        idx = max(0, min(idx, 19999));
        A[m][t] = E[(size_t)idx * 256 + t];
    }
    __syncthreads();

    // ---- per-row norm + log_map scale (wave w handles rows 2w, 2w+1) ----
#pragma unroll
    for (int rr = 0; rr < 2; ++rr) {
        int m = wave * 2 + rr;
        float ss = 0.f;
#pragma unroll
        for (int i = 0; i < 4; ++i) {
            float v = A[m][lane + 64 * i];
            ss = fmaf(v, v, ss);
        }
        ss = wred(ss);
        float n = fmaxf(sqrtf(ss), EPSF);
        float arg = fminf(SQRT_C * n, 1.f - 1e-5f);
        float s = atanhf(arg) / (SQRT_C * n);
        if (lane == 0) scale[m] = s;
    }
    __syncthreads();
#pragma unroll
    for (int m = 0; m < 8; ++m) A[m][t] *= scale[m];
    __syncthreads();

    // ---- dual GEMV: acc[0..3] = s_log @ W_s, acc[4..7] = o_log @ W_o ----
    float acc[8] = {};
    for (int k = 0; k < 256; k += 4) {
        float av[8][4];
#pragma unroll
        for (int m = 0; m < 8; ++m) {
            float4 q = *(const float4*)&A[m][k];
            av[m][0] = q.x; av[m][1] = q.y; av[m][2] = q.z; av[m][3] = q.w;
        }
#pragma unroll
        for (int j = 0; j < 4; ++j) {
            float ws = Ws[(size_t)(k + j) * 256 + t];
            float wo = Wo[(size_t)(k + j) * 256 + t];
#pragma unroll
            for (int m = 0; m < 4; ++m) {
                acc[m]     = fmaf(av[m][j],     ws, acc[m]);
                acc[4 + m] = fmaf(av[4 + m][j], wo, acc[4 + m]);
            }
        }
    }
    __syncthreads();   // A dead, reuse for tan rows
#pragma unroll
    for (int m = 0; m < 8; ++m) A[m][t] = acc[m];
    __syncthreads();

    // ---- exp_map + mobius_add(-s_h, o_h): wave w handles b = b0+w ----
    {
        float sv[4], ov[4];
        float sss = 0.f, sso = 0.f, sdot = 0.f;
#pragma unroll
        for (int i = 0; i < 4; ++i) {
            sv[i] = A[wave][lane + 64 * i];
            ov[i] = A[4 + wave][lane + 64 * i];
            sss = fmaf(sv[i], sv[i], sss);
            sso = fmaf(ov[i], ov[i], sso);
            sdot = fmaf(sv[i], ov[i], sdot);
        }
        sss = wred(sss); sso = wred(sso); sdot = wred(sdot);
        float ns = fmaxf(sqrtf(sss), EPSF);
        float no = fmaxf(sqrtf(sso), EPSF);
        float scs = tanhf(SQRT_C * ns) / (SQRT_C * ns);
        float sco = tanhf(SQRT_C * no) / (SQRT_C * no);
        float x2 = scs * scs * sss;
        float yy2 = sco * sco * sso;
        float xy = -scs * sco * sdot;
        float a1 = 1.f + 2.f * CCF * xy + CCF * yy2;
        float b1 = 1.f - CCF * x2;
        float den = 1.f + 2.f * CCF * xy + CCF * CCF * x2 * yy2 + EPSF;
        float rden = 1.f / den;
        float qq = 0.f;
#pragma unroll
        for (int i = 0; i < 4; ++i) {
            float num = a1 * (-scs * sv[i]) + b1 * (sco * ov[i]);
            float qv = num * rden;
            qq = fmaf(qv, qv, qq);
            C[wave][lane + 64 * i] = qv;
        }
        qq = wred(qq);
        if (lane == 0) q2s[wave] = qq;
    }
    __syncthreads();

    // ---- scores: G = query . rel_h^T + closed-form mobius distance ----
#pragma unroll
    for (int jj = 0; jj < 2; ++jj) {
        int r = jj * 256 + t;
        float acc4[4] = {};
        for (int k = 0; k < 256; k += 4) {
            float qv[4][4];
#pragma unroll
            for (int m = 0; m < 4; ++m) {
                float4 q = *(const float4*)&C[m][k];
                qv[m][0] = q.x; qv[m][1] = q.y; qv[m][2] = q.z; qv[m][3] = q.w;
            }
#pragma unroll
            for (int j = 0; j < 4; ++j) {
                float w = rel_hT[(size_t)(k + j) * 512 + r];
#pragma unroll
                for (int m = 0; m < 4; ++m)
                    acc4[m] = fmaf(qv[m][j], w, acc4[m]);
            }
        }
        float y2r = y2[r];
        float rb = rbias[r];
#pragma unroll
        for (int m = 0; m < 4; ++m) {
            float xy = -acc4[m];       // dot(-query, rel_h)
            float x2 = q2s[m];
            float a1 = 1.f + 2.f * CCF * xy + CCF * y2r;
            float b1 = 1.f - CCF * x2;
            float den = 1.f + 2.f * CCF * xy + CCF * CCF * x2 * y2r + EPSF;
            float num2 = a1 * a1 * x2 + 2.f * a1 * b1 * xy + b1 * b1 * y2r;
            out[(size_t)(b0 + m) * 512 + r] = -(num2 / (den * den)) + rb;
        }
    }
}

extern "C" void kernel_launch(void* const* d_in, const int* in_sizes, int n_in,
                              void* d_out, int out_size, void* d_ws, size_t ws_size,
                              hipStream_t stream) {
    const float* E = (const float*)d_in[0];          // 20000 x 256
    const float* rel = (const float*)d_in[1];        // 512 x 256
    const int* trip = (const int*)d_in[2];           // 1024 x 3 (int32)
    const float* Ws = (const float*)d_in[3];         // 256 x 256
    const float* Wo = (const float*)d_in[4];         // 256 x 256
    const float* rbias = (const float*)d_in[5];      // 512
    float* out = (float*)d_out;                      // 1024 x 512

    float* ws = (float*)d_ws;
    float* rel_hT = ws;                  // 256*512 = 131072
    float* y2     = rel_hT + 131072;     // 512

    k_rel<<<128, 256, 0, stream>>>(rel, rel_hT, y2);
    k_main<<<256, 256, 0, stream>>>(E, trip, Ws, Wo, rel_hT, y2, rbias, out);
}

// Round 4
// 31.917 us; speedup vs baseline: 2.0453x; 1.4756x over previous
//
#include <hip/hip_runtime.h>
#include <math.h>

#define EPSF 1e-6f
#define CCF  0.01f
#define SQRT_C 0.1f

__device__ __forceinline__ float wred(float v) {
#pragma unroll
    for (int o = 32; o > 0; o >>= 1) v += __shfl_xor(v, o, 64);
    return v;
}

// rel_h = exp_map_zero(rel_embedding); store transposed (256 x 512) + y2[r].
__global__ __launch_bounds__(256) void k_rel(const float* __restrict__ rel,
                                             float* __restrict__ rel_hT,
                                             float* __restrict__ y2) {
    int wave = threadIdx.x >> 6, lane = threadIdx.x & 63;
    int r = blockIdx.x * 4 + wave;  // 0..511
    float v[4];
    float ss = 0.f;
#pragma unroll
    for (int i = 0; i < 4; ++i) {
        v[i] = rel[(size_t)r * 256 + lane + 64 * i];
        ss = fmaf(v[i], v[i], ss);
    }
    ss = wred(ss);
    float n = fmaxf(sqrtf(ss), EPSF);
    float s = tanhf(SQRT_C * n) / (SQRT_C * n);
#pragma unroll
    for (int i = 0; i < 4; ++i) {
        rel_hT[(size_t)(lane + 64 * i) * 512 + r] = s * v[i];
    }
    if (lane == 0) y2[r] = s * s * ss;
}

// Fully fused main kernel. 256 blocks x 512 threads (8 waves), 4 batch rows/block.
// Phase layout:
//   gather+log (wave w owns row w of A[8][256])
//   dual GEMV: threads 0-255 -> W_s cols, 256-511 -> W_o cols
//   exp_map+mobius -> query C[4][256] (waves 0-3)
//   scores: thread t owns output column t (512 cols)
__global__ __launch_bounds__(512) void k_main(const float* __restrict__ E,
                                              const int* __restrict__ trip,
                                              const float* __restrict__ Ws,
                                              const float* __restrict__ Wo,
                                              const float* __restrict__ rel_hT,
                                              const float* __restrict__ y2,
                                              const float* __restrict__ rbias,
                                              float* __restrict__ out) {
    __shared__ float A[8][256];     // rows 0-3: s_log rows, 4-7: o_log rows (then tan rows)
    __shared__ float C[4][256];     // query rows
    __shared__ float q2s[4];

    int b0 = blockIdx.x * 4;
    int t = threadIdx.x;            // 0..511
    int wave = t >> 6, lane = t & 63;

    // ---- gather row `wave` + log_map scale (all per-wave, no LDS round-trip) ----
    {
        int b = b0 + (wave & 3);
        int col = (wave >> 2) ? 2 : 0;
        int idx = trip[b * 3 + col];
        idx = max(0, min(idx, 19999));
        float4 v = *(const float4*)(E + (size_t)idx * 256 + lane * 4);
        float ss = v.x * v.x;
        ss = fmaf(v.y, v.y, ss);
        ss = fmaf(v.z, v.z, ss);
        ss = fmaf(v.w, v.w, ss);
        ss = wred(ss);              // full sum in every lane
        float n = fmaxf(sqrtf(ss), EPSF);
        float arg = fminf(SQRT_C * n, 1.f - 1e-5f);
        float s = atanhf(arg) / (SQRT_C * n);
        v.x *= s; v.y *= s; v.z *= s; v.w *= s;
        *(float4*)&A[wave][lane * 4] = v;
    }
    __syncthreads();

    // ---- dual GEMV: half 0 computes s_log@W_s, half 1 computes o_log@W_o ----
    int half = t >> 8;              // wave-uniform
    int colw = t & 255;
    {
        const float* __restrict__ W = half ? Wo : Ws;
        int r0 = half * 4;
        float acc[4] = {};
        for (int k = 0; k < 256; k += 8) {
#pragma unroll
            for (int j = 0; j < 8; ++j) {
                float w = W[(size_t)(k + j) * 256 + colw];
                acc[0] = fmaf(A[r0 + 0][k + j], w, acc[0]);
                acc[1] = fmaf(A[r0 + 1][k + j], w, acc[1]);
                acc[2] = fmaf(A[r0 + 2][k + j], w, acc[2]);
                acc[3] = fmaf(A[r0 + 3][k + j], w, acc[3]);
            }
        }
        __syncthreads();            // done reading A
#pragma unroll
        for (int m = 0; m < 4; ++m) A[r0 + m][colw] = acc[m];
    }
    __syncthreads();

    // ---- exp_map + mobius_add(-s_h, o_h): waves 0-3, wave w owns pair b0+w ----
    if (wave < 4) {
        float sv[4], ov[4];
        float sss = 0.f, sso = 0.f, sdot = 0.f;
#pragma unroll
        for (int i = 0; i < 4; ++i) {
            sv[i] = A[wave][lane + 64 * i];
            ov[i] = A[4 + wave][lane + 64 * i];
            sss = fmaf(sv[i], sv[i], sss);
            sso = fmaf(ov[i], ov[i], sso);
            sdot = fmaf(sv[i], ov[i], sdot);
        }
        sss = wred(sss); sso = wred(sso); sdot = wred(sdot);
        float ns = fmaxf(sqrtf(sss), EPSF);
        float no = fmaxf(sqrtf(sso), EPSF);
        float scs = tanhf(SQRT_C * ns) / (SQRT_C * ns);
        float sco = tanhf(SQRT_C * no) / (SQRT_C * no);
        float x2 = scs * scs * sss;
        float yy2 = sco * sco * sso;
        float xy = -scs * sco * sdot;
        float a1 = 1.f + 2.f * CCF * xy + CCF * yy2;
        float b1 = 1.f - CCF * x2;
        float den = 1.f + 2.f * CCF * xy + CCF * CCF * x2 * yy2 + EPSF;
        float rden = 1.f / den;
        float qq = 0.f;
#pragma unroll
        for (int i = 0; i < 4; ++i) {
            float num = a1 * (-scs * sv[i]) + b1 * (sco * ov[i]);
            float qv = num * rden;
            qq = fmaf(qv, qv, qq);
            C[wave][lane + 64 * i] = qv;
        }
        qq = wred(qq);
        if (lane == 0) q2s[wave] = qq;
    }
    __syncthreads();

    // ---- scores: thread t owns column r=t; closed-form mobius distance ----
    {
        int r = t;
        float y2r = y2[r];
        float rb = rbias[r];
        float acc4[4] = {};
        for (int k = 0; k < 256; k += 8) {
#pragma unroll
            for (int j = 0; j < 8; ++j) {
                float w = rel_hT[(size_t)(k + j) * 512 + r];
                acc4[0] = fmaf(C[0][k + j], w, acc4[0]);
                acc4[1] = fmaf(C[1][k + j], w, acc4[1]);
                acc4[2] = fmaf(C[2][k + j], w, acc4[2]);
                acc4[3] = fmaf(C[3][k + j], w, acc4[3]);
            }
        }
#pragma unroll
        for (int m = 0; m < 4; ++m) {
            float xy = -acc4[m];       // dot(-query, rel_h)
            float x2 = q2s[m];
            float a1 = 1.f + 2.f * CCF * xy + CCF * y2r;
            float b1 = 1.f - CCF * x2;
            float den = 1.f + 2.f * CCF * xy + CCF * CCF * x2 * y2r + EPSF;
            float num2 = a1 * a1 * x2 + 2.f * a1 * b1 * xy + b1 * b1 * y2r;
            out[(size_t)(b0 + m) * 512 + r] = -(num2 / (den * den)) + rb;
        }
    }
}

extern "C" void kernel_launch(void* const* d_in, const int* in_sizes, int n_in,
                              void* d_out, int out_size, void* d_ws, size_t ws_size,
                              hipStream_t stream) {
    const float* E = (const float*)d_in[0];          // 20000 x 256
    const float* rel = (const float*)d_in[1];        // 512 x 256
    const int* trip = (const int*)d_in[2];           // 1024 x 3 (int32)
    const float* Ws = (const float*)d_in[3];         // 256 x 256
    const float* Wo = (const float*)d_in[4];         // 256 x 256
    const float* rbias = (const float*)d_in[5];      // 512
    float* out = (float*)d_out;                      // 1024 x 512

    float* ws = (float*)d_ws;
    float* rel_hT = ws;                  // 256*512 = 131072
    float* y2     = rel_hT + 131072;     // 512

    k_rel<<<128, 256, 0, stream>>>(rel, rel_hT, y2);
    k_main<<<256, 512, 0, stream>>>(E, trip, Ws, Wo, rel_hT, y2, rbias, out);
}

// Round 5
// 28.503 us; speedup vs baseline: 2.2903x; 1.1198x over previous
//
#include <hip/hip_runtime.h>
#include <math.h>

#define EPSF 1e-6f
#define CCF  0.01f
#define SQRT_C 0.1f

__device__ __forceinline__ float wred(float v) {
#pragma unroll
    for (int o = 32; o > 0; o >>= 1) v += __shfl_xor(v, o, 64);
    return v;
}

// rel_h = exp_map_zero(rel_embedding); store transposed (256 x 512) + y2[r].
__global__ __launch_bounds__(256) void k_rel(const float* __restrict__ rel,
                                             float* __restrict__ rel_hT,
                                             float* __restrict__ y2) {
    int wave = threadIdx.x >> 6, lane = threadIdx.x & 63;
    int r = blockIdx.x * 4 + wave;  // 0..511
    float v[4];
    float ss = 0.f;
#pragma unroll
    for (int i = 0; i < 4; ++i) {
        v[i] = rel[(size_t)r * 256 + lane + 64 * i];
        ss = fmaf(v[i], v[i], ss);
    }
    ss = wred(ss);
    float n = fmaxf(sqrtf(ss), EPSF);
    float s = tanhf(SQRT_C * n) / (SQRT_C * n);
#pragma unroll
    for (int i = 0; i < 4; ++i) {
        rel_hT[(size_t)(lane + 64 * i) * 512 + r] = s * v[i];
    }
    if (lane == 0) y2[r] = s * s * ss;
}

// Fully fused main kernel. 256 blocks x 1024 threads (16 waves), 4 batch rows/block.
//   gather+log:  waves 0-7, wave w owns row w of A[8][256]
//   dual GEMV:   4 groups of 256 threads: (s|o) x (k-lo|k-hi), partials via SP
//   mobius:      waves 0-3 -> query C[4][256], q2s
//   scores:      thread groups (t&511 = column r) x (k-lo|k-hi), partials via SP
__global__ __launch_bounds__(1024) void k_main(const float* __restrict__ E,
                                               const int* __restrict__ trip,
                                               const float* __restrict__ Ws,
                                               const float* __restrict__ Wo,
                                               const float* __restrict__ rel_hT,
                                               const float* __restrict__ y2,
                                               const float* __restrict__ rbias,
                                               float* __restrict__ out) {
    __shared__ float A[8][256];    // log-mapped gathered rows (0-3 s, 4-7 o)
    __shared__ float T[8][256];    // tangent rows (GEMV result)
    __shared__ float C[4][256];    // query rows
    __shared__ float SP[8][256];   // partial-sum scratch (reused both phases)
    __shared__ float q2s[4];

    int b0 = blockIdx.x * 4;
    int t = threadIdx.x;            // 0..1023
    int wave = t >> 6, lane = t & 63;

    // ---- gather + log_map (waves 0-7) ----
    if (wave < 8) {
        int b = b0 + (wave & 3);
        int col = (wave >> 2) ? 2 : 0;
        int idx = trip[b * 3 + col];
        idx = max(0, min(idx, 19999));
        float4 v = *(const float4*)(E + (size_t)idx * 256 + lane * 4);
        float ss = v.x * v.x;
        ss = fmaf(v.y, v.y, ss);
        ss = fmaf(v.z, v.z, ss);
        ss = fmaf(v.w, v.w, ss);
        ss = wred(ss);
        float n = fmaxf(sqrtf(ss), EPSF);
        float arg = fminf(SQRT_C * n, 1.f - 1e-5f);
        float s = atanhf(arg) / (SQRT_C * n);
        v.x *= s; v.y *= s; v.z *= s; v.w *= s;
        *(float4*)&A[wave][lane * 4] = v;
    }
    __syncthreads();

    // ---- dual GEMV, k-split: group g = (s|o, k-half) ----
    {
        int g = t >> 8;            // 0..3 (wave-uniform)
        int halfsel = g & 1;       // 0: s rows @ Ws, 1: o rows @ Wo
        int kh = g >> 1;           // k half
        int colw = t & 255;
        int r0 = halfsel * 4;
        const float* __restrict__ W = halfsel ? Wo : Ws;
        int kb = kh * 128;
        float acc0 = 0.f, acc1 = 0.f, acc2 = 0.f, acc3 = 0.f;
#pragma unroll 2
        for (int k = 0; k < 128; k += 4) {
            float4 a0 = *(const float4*)&A[r0 + 0][kb + k];
            float4 a1 = *(const float4*)&A[r0 + 1][kb + k];
            float4 a2 = *(const float4*)&A[r0 + 2][kb + k];
            float4 a3 = *(const float4*)&A[r0 + 3][kb + k];
            float w0 = W[(size_t)(kb + k + 0) * 256 + colw];
            float w1 = W[(size_t)(kb + k + 1) * 256 + colw];
            float w2 = W[(size_t)(kb + k + 2) * 256 + colw];
            float w3 = W[(size_t)(kb + k + 3) * 256 + colw];
            acc0 = fmaf(a0.w, w3, fmaf(a0.z, w2, fmaf(a0.y, w1, fmaf(a0.x, w0, acc0))));
            acc1 = fmaf(a1.w, w3, fmaf(a1.z, w2, fmaf(a1.y, w1, fmaf(a1.x, w0, acc1))));
            acc2 = fmaf(a2.w, w3, fmaf(a2.z, w2, fmaf(a2.y, w1, fmaf(a2.x, w0, acc2))));
            acc3 = fmaf(a3.w, w3, fmaf(a3.z, w2, fmaf(a3.y, w1, fmaf(a3.x, w0, acc3))));
        }
        if (kh) {
            SP[r0 + 0][colw] = acc0;
            SP[r0 + 1][colw] = acc1;
            SP[r0 + 2][colw] = acc2;
            SP[r0 + 3][colw] = acc3;
        }
        __syncthreads();
        if (!kh) {
            T[r0 + 0][colw] = acc0 + SP[r0 + 0][colw];
            T[r0 + 1][colw] = acc1 + SP[r0 + 1][colw];
            T[r0 + 2][colw] = acc2 + SP[r0 + 2][colw];
            T[r0 + 3][colw] = acc3 + SP[r0 + 3][colw];
        }
    }
    __syncthreads();

    // ---- exp_map + mobius_add(-s_h, o_h): waves 0-3, wave w owns b0+w ----
    if (wave < 4) {
        float sv[4], ov[4];
        float sss = 0.f, sso = 0.f, sdot = 0.f;
#pragma unroll
        for (int i = 0; i < 4; ++i) {
            sv[i] = T[wave][lane + 64 * i];
            ov[i] = T[4 + wave][lane + 64 * i];
            sss = fmaf(sv[i], sv[i], sss);
            sso = fmaf(ov[i], ov[i], sso);
            sdot = fmaf(sv[i], ov[i], sdot);
        }
        sss = wred(sss); sso = wred(sso); sdot = wred(sdot);
        float ns = fmaxf(sqrtf(sss), EPSF);
        float no = fmaxf(sqrtf(sso), EPSF);
        float scs = tanhf(SQRT_C * ns) / (SQRT_C * ns);
        float sco = tanhf(SQRT_C * no) / (SQRT_C * no);
        float x2 = scs * scs * sss;
        float yy2 = sco * sco * sso;
        float xy = -scs * sco * sdot;
        float a1 = 1.f + 2.f * CCF * xy + CCF * yy2;
        float b1 = 1.f - CCF * x2;
        float den = 1.f + 2.f * CCF * xy + CCF * CCF * x2 * yy2 + EPSF;
        float rden = 1.f / den;
        float qq = 0.f;
#pragma unroll
        for (int i = 0; i < 4; ++i) {
            float num = a1 * (-scs * sv[i]) + b1 * (sco * ov[i]);
            float qv = num * rden;
            qq = fmaf(qv, qv, qq);
            C[wave][lane + 64 * i] = qv;
        }
        qq = wred(qq);
        if (lane == 0) q2s[wave] = qq;
    }
    __syncthreads();

    // ---- scores, k-split: thread (r = t&511, kh2 = t>>9) ----
    {
        int r = t & 511;
        int kh2 = t >> 9;
        int kb = kh2 * 128;
        float* sp = &SP[0][0];
        float s0 = 0.f, s1 = 0.f, s2 = 0.f, s3 = 0.f;
#pragma unroll 2
        for (int k = 0; k < 128; k += 4) {
            float4 c0 = *(const float4*)&C[0][kb + k];
            float4 c1 = *(const float4*)&C[1][kb + k];
            float4 c2 = *(const float4*)&C[2][kb + k];
            float4 c3 = *(const float4*)&C[3][kb + k];
            float w0 = rel_hT[(size_t)(kb + k + 0) * 512 + r];
            float w1 = rel_hT[(size_t)(kb + k + 1) * 512 + r];
            float w2 = rel_hT[(size_t)(kb + k + 2) * 512 + r];
            float w3 = rel_hT[(size_t)(kb + k + 3) * 512 + r];
            s0 = fmaf(c0.w, w3, fmaf(c0.z, w2, fmaf(c0.y, w1, fmaf(c0.x, w0, s0))));
            s1 = fmaf(c1.w, w3, fmaf(c1.z, w2, fmaf(c1.y, w1, fmaf(c1.x, w0, s1))));
            s2 = fmaf(c2.w, w3, fmaf(c2.z, w2, fmaf(c2.y, w1, fmaf(c2.x, w0, s2))));
            s3 = fmaf(c3.w, w3, fmaf(c3.z, w2, fmaf(c3.y, w1, fmaf(c3.x, w0, s3))));
        }
        if (kh2) {
            sp[0 * 512 + r] = s0;
            sp[1 * 512 + r] = s1;
            sp[2 * 512 + r] = s2;
            sp[3 * 512 + r] = s3;
        }
        __syncthreads();
        if (!kh2) {
            s0 += sp[0 * 512 + r];
            s1 += sp[1 * 512 + r];
            s2 += sp[2 * 512 + r];
            s3 += sp[3 * 512 + r];
            float dots[4] = {s0, s1, s2, s3};
            float y2r = y2[r];
            float rb = rbias[r];
#pragma unroll
            for (int m = 0; m < 4; ++m) {
                float xy = -dots[m];     // dot(-query, rel_h)
                float x2 = q2s[m];
                float a1 = 1.f + 2.f * CCF * xy + CCF * y2r;
                float b1 = 1.f - CCF * x2;
                float den = 1.f + 2.f * CCF * xy + CCF * CCF * x2 * y2r + EPSF;
                float num2 = a1 * a1 * x2 + 2.f * a1 * b1 * xy + b1 * b1 * y2r;
                out[(size_t)(b0 + m) * 512 + r] = -(num2 / (den * den)) + rb;
            }
        }
    }
}

extern "C" void kernel_launch(void* const* d_in, const int* in_sizes, int n_in,
                              void* d_out, int out_size, void* d_ws, size_t ws_size,
                              hipStream_t stream) {
    const float* E = (const float*)d_in[0];          // 20000 x 256
    const float* rel = (const float*)d_in[1];        // 512 x 256
    const int* trip = (const int*)d_in[2];           // 1024 x 3 (int32)
    const float* Ws = (const float*)d_in[3];         // 256 x 256
    const float* Wo = (const float*)d_in[4];         // 256 x 256
    const float* rbias = (const float*)d_in[5];      // 512
    float* out = (float*)d_out;                      // 1024 x 512

    float* ws = (float*)d_ws;
    float* rel_hT = ws;                  // 256*512 = 131072
    float* y2     = rel_hT + 131072;     // 512

    k_rel<<<128, 256, 0, stream>>>(rel, rel_hT, y2);
    k_main<<<256, 1024, 0, stream>>>(E, trip, Ws, Wo, rel_hT, y2, rbias, out);
}